// Round 5
// baseline (949.866 us; speedup 1.0000x reference)
//
#include <hip/hip_runtime.h>
#include <hip/hip_bf16.h>

#define HD 256
#define CD 512
#define VD 32000
#define ND 64
#define TD 512

typedef __attribute__((ext_vector_type(8))) short short8;
typedef __attribute__((ext_vector_type(4))) float floatx4;
typedef __attribute__((ext_vector_type(8))) int int32x8;

__device__ inline float bf2f(unsigned short u) {
  union { unsigned u; float f; } t; t.u = ((unsigned)u) << 16; return t.f;
}
__device__ inline unsigned short f2bf(float x) {
  union { float f; unsigned u; } t; t.f = x;
  unsigned u = t.u;
  u += 0x7FFFu + ((u >> 16) & 1u);
  return (unsigned short)(u >> 16);
}
__device__ inline float bf_lo(unsigned u) { union { unsigned u; float f; } t; t.u = u << 16; return t.f; }
__device__ inline float bf_hi(unsigned u) { union { unsigned u; float f; } t; t.u = u & 0xFFFF0000u; return t.f; }

__device__ inline floatx4 zf4() { floatx4 v; v[0] = v[1] = v[2] = v[3] = 0.f; return v; }
__device__ inline floatx4 mfma16(short8 a, short8 b, floatx4 c) {
  return __builtin_amdgcn_mfma_f32_16x16x32_bf16(a, b, c, 0, 0, 0);
}
// MX-scaled fp8 MFMA, scales pinned to 1.0 (E8M0 bias 127 = 0x7F)
__device__ inline floatx4 mfma_mx(int32x8 a, int32x8 b, floatx4 c) {
  return __builtin_amdgcn_mfma_scale_f32_16x16x128_f8f6f4(
      a, b, c, 0, 0, 0, 0x7F7F7F7F, 0, 0x7F7F7F7F);
}

// ---------------- fused start pipeline: fx -> 2 ResLayers -> log_softmax ----------------
__global__ void k_start(const float* __restrict__ emb, const float* __restrict__ W,
                        const float* __restrict__ bb, const float* __restrict__ rw,
                        const float* __restrict__ rb, const float* __restrict__ nextE,
                        float* __restrict__ startO) {
  __shared__ float x[HD], h[HD];
  __shared__ float red[4];
  int j = threadIdx.x;
  x[j] = emb[j];
  __syncthreads();
  float a = bb[j];
#pragma unroll 4
  for (int i = 0; i < HD; ++i) a += x[i] * W[i * HD + j];
  __syncthreads();
  x[j] = a;
  __syncthreads();
  for (int L = 0; L < 2; ++L) {
    const float* w1 = rw + (size_t)(L * 2 + 0) * HD * HD;
    const float* b1 = rb + (L * 2 + 0) * HD;
    const float* w2 = rw + (size_t)(L * 2 + 1) * HD * HD;
    const float* b2 = rb + (L * 2 + 1) * HD;
    float t = b1[j];
#pragma unroll 4
    for (int i = 0; i < HD; ++i) t += x[i] * w1[i * HD + j];
    t = fmaxf(t, 0.f);
    h[j] = t;
    __syncthreads();
    float o = b2[j];
#pragma unroll 4
    for (int i = 0; i < HD; ++i) o += h[i] * w2[i * HD + j];
    o = x[j] + fmaxf(o, 0.f);
    __syncthreads();
    x[j] = o;
    __syncthreads();
  }
  float lg0 = 0.f, lg1 = 0.f;
#pragma unroll 4
  for (int hh = 0; hh < HD; ++hh) {
    float xv = x[hh];
    lg0 += xv * nextE[j * HD + hh];
    lg1 += xv * nextE[(j + 256) * HD + hh];
  }
  float m = fmaxf(lg0, lg1);
#pragma unroll
  for (int sh = 1; sh <= 32; sh <<= 1) m = fmaxf(m, __shfl_xor(m, sh));
  if ((j & 63) == 0) red[j >> 6] = m;
  __syncthreads();
  m = fmaxf(fmaxf(red[0], red[1]), fmaxf(red[2], red[3]));
  __syncthreads();
  float s = __expf(lg0 - m) + __expf(lg1 - m);
#pragma unroll
  for (int sh = 1; sh <= 32; sh <<= 1) s += __shfl_xor(s, sh);
  if ((j & 63) == 0) red[j >> 6] = s;
  __syncthreads();
  s = red[0] + red[1] + red[2] + red[3];
  float ls = __logf(s);
  startO[j] = lg0 - m - ls;
  startO[j + 256] = lg1 - m - ls;
}

// x (rows x 256) -> two ResLayers -> out  (one block per row, 256 threads)
__global__ void k_mlp(const float* __restrict__ inp, const float* __restrict__ rw,
                      const float* __restrict__ rb, float* __restrict__ out) {
  __shared__ float x[HD], h[HD];
  int j = threadIdx.x;
  int row = blockIdx.x;
  x[j] = inp[row * HD + j];
  __syncthreads();
  for (int L = 0; L < 2; ++L) {
    const float* w1 = rw + (size_t)(L * 2 + 0) * HD * HD;
    const float* b1 = rb + (L * 2 + 0) * HD;
    const float* w2 = rw + (size_t)(L * 2 + 1) * HD * HD;
    const float* b2 = rb + (L * 2 + 1) * HD;
    float a = b1[j];
#pragma unroll 4
    for (int i = 0; i < HD; ++i) a += x[i] * w1[i * HD + j];
    a = fmaxf(a, 0.f);
    h[j] = a;
    __syncthreads();
    float o = b2[j];
#pragma unroll 4
    for (int i = 0; i < HD; ++i) o += h[i] * w2[i * HD + j];
    o = x[j] + fmaxf(o, 0.f);
    __syncthreads();
    x[j] = o;
    __syncthreads();
  }
  out[row * HD + j] = x[j];
}

// ---------------- generic NT GEMM (M x 256) x (N x 256)^T -> bf16 out[M][N] ----------------
#define GEMM_LDS (2 * 128 * 528)
__global__ __launch_bounds__(512) void k_gemm(const float* __restrict__ A,
                                              const float* __restrict__ B,
                                              unsigned short* __restrict__ out,
                                              int ldo) {
  extern __shared__ char smem[];
  char* sA = smem;             // [128][528 bytes] bf16, K contiguous
  char* sB = smem + 128 * 528;
  const int tid = threadIdx.x;
  const int mbase = blockIdx.x * 128, nbase = blockIdx.y * 128;
  {
    int row = tid >> 2, seg = tid & 3;
    const float4* srcA = (const float4*)(A + (size_t)(mbase + row) * HD + seg * 64);
    const float4* srcB = (const float4*)(B + (size_t)(nbase + row) * HD + seg * 64);
    uint2* dA = (uint2*)(sA + row * 528 + seg * 128);
    uint2* dB = (uint2*)(sB + row * 528 + seg * 128);
#pragma unroll
    for (int i = 0; i < 16; ++i) {
      float4 va = srcA[i];
      float4 vb = srcB[i];
      dA[i] = make_uint2((unsigned)f2bf(va.x) | ((unsigned)f2bf(va.y) << 16),
                         (unsigned)f2bf(va.z) | ((unsigned)f2bf(va.w) << 16));
      dB[i] = make_uint2((unsigned)f2bf(vb.x) | ((unsigned)f2bf(vb.y) << 16),
                         (unsigned)f2bf(vb.z) | ((unsigned)f2bf(vb.w) << 16));
    }
  }
  __syncthreads();
  const int w = tid >> 6, l = tid & 63, l15 = l & 15, quad = l >> 4;
  floatx4 acc[8];
#pragma unroll
  for (int nt = 0; nt < 8; ++nt) acc[nt] = zf4();
  const char* arow = sA + (w * 16 + l15) * 528 + quad * 16;
  const char* brow = sB + l15 * 528 + quad * 16;
#pragma unroll
  for (int kc = 0; kc < 8; ++kc) {
    short8 a = *(const short8*)(arow + kc * 64);
#pragma unroll
    for (int nt = 0; nt < 8; ++nt) {
      short8 b = *(const short8*)(brow + nt * 16 * 528 + kc * 64);
      acc[nt] = mfma16(a, b, acc[nt]);
    }
  }
#pragma unroll
  for (int nt = 0; nt < 8; ++nt)
#pragma unroll
    for (int r = 0; r < 4; ++r) {
      int m = mbase + w * 16 + quad * 4 + r;
      int n = nbase + nt * 16 + l15;
      out[(size_t)m * ldo + n] = f2bf(acc[nt][r]);
    }
}

// ---------------- transition row-softmax -> P fp8 (x512 scale) ----------------
__global__ void k_smrow(const unsigned short* __restrict__ lg, unsigned char* __restrict__ P8) {
  __shared__ float red[4];
  int row = blockIdx.x, j = threadIdx.x;
  float v0 = bf2f(lg[row * CD + j]);
  float v1 = bf2f(lg[row * CD + 256 + j]);
  float m = fmaxf(v0, v1);
#pragma unroll
  for (int sh = 1; sh <= 32; sh <<= 1) m = fmaxf(m, __shfl_xor(m, sh));
  if ((j & 63) == 0) red[j >> 6] = m;
  __syncthreads();
  m = fmaxf(fmaxf(red[0], red[1]), fmaxf(red[2], red[3]));
  __syncthreads();
  float e0 = __expf(v0 - m), e1 = __expf(v1 - m);
  float s = e0 + e1;
#pragma unroll
  for (int sh = 1; sh <= 32; sh <<= 1) s += __shfl_xor(s, sh);
  if ((j & 63) == 0) red[j >> 6] = s;
  __syncthreads();
  s = red[0] + red[1] + red[2] + red[3];
  float inv = 512.0f / s;   // gamma_P = 512 folded in
  int b0 = __builtin_amdgcn_cvt_pk_fp8_f32(e0 * inv, e0 * inv, 0, false);
  int b1 = __builtin_amdgcn_cvt_pk_fp8_f32(e1 * inv, e1 * inv, 0, false);
  P8[row * CD + j] = (unsigned char)(b0 & 0xff);
  P8[row * CD + 256 + j] = (unsigned char)(b1 & 0xff);
}

// transpose fp8 512x512: P8 -> PT8
__global__ __launch_bounds__(256) void k_tr8(const unsigned char* __restrict__ P,
                                             unsigned char* __restrict__ PT) {
  __shared__ unsigned char t[128][144];
  int rb = blockIdx.x * 128, cb = blockIdx.y * 128;
  int tid = threadIdx.x;
  {
    int r = tid >> 1, h = tid & 1;
    const uint4* src = (const uint4*)(P + (size_t)(rb + r) * CD + cb + h * 64);
    uint4* dst = (uint4*)(&t[r][h * 64]);
#pragma unroll
    for (int i = 0; i < 4; ++i) dst[i] = src[i];
  }
  __syncthreads();
  {
    int c = tid >> 1, h = tid & 1;
    unsigned char buf[64];
#pragma unroll
    for (int i = 0; i < 64; ++i) buf[i] = t[h * 64 + i][c];
    uint4* dst = (uint4*)(PT + (size_t)(cb + c) * CD + rb + h * 64);
    const uint4* s = (const uint4*)buf;
#pragma unroll
    for (int i = 0; i < 4; ++i) dst[i] = s[i];
  }
}

// ---------------- vocab log-sum-exp over columns of logT [V][C] ----------------
__global__ __launch_bounds__(512) void k_lsep(const unsigned short* __restrict__ logT,
                                              float* __restrict__ part) {
  int c = threadIdx.x, b = blockIdx.x;
  const unsigned short* p = logT + (size_t)b * 256 * CD + c;
  float m = -1e30f, s = 0.f;
  for (int i = 0; i < 256; ++i) {
    float v = bf2f(p[(size_t)i * CD]);
    float nm = fmaxf(m, v);
    s = s * __expf(m - nm) + __expf(v - nm);
    m = nm;
  }
  part[b * 1024 + c] = m;
  part[b * 1024 + 512 + c] = s;
}

__global__ void k_lsef(const float* __restrict__ part, float* __restrict__ lse) {
  int c = threadIdx.x;
  float m = -1e30f, s = 0.f;
  for (int i = 0; i < 125; ++i) {
    float mi = part[i * 1024 + c], si = part[i * 1024 + 512 + c];
    float nm = fmaxf(m, mi);
    s = s * __expf(m - nm) + si * __expf(mi - nm);
    m = nm;
  }
  lse[c] = m + __logf(s);
}

// ---------------- gather E = exp(emission log-prob) ----------------
// 8 groups of 16 seqs; lane o holds n = q*16 + (o&15),
// value j = nt*4+r at c = w*64 + nt*16 + (o>>4)*4 + r
__global__ __launch_bounds__(512) void k_gather(const int* __restrict__ text,
                                                const unsigned short* __restrict__ logT,
                                                const float* __restrict__ lse,
                                                unsigned short* __restrict__ em) {
  const int b = blockIdx.x;
  const int g = b >> 8, t = b & 255;
  const int dir = g >> 2, q = g & 3;
  const int tg = dir ? (511 - t) : t;
  const int tid = threadIdx.x, w = tid >> 6, l = tid & 63;
  const int l15 = l & 15, quad = l >> 4;
  const int n = q * 16 + l15;
  const int tok = text[n * TD + tg];
  const unsigned short* row = logT + (size_t)tok * CD;
  unsigned outp[8];
#pragma unroll
  for (int nt = 0; nt < 4; ++nt) {
    int c0 = w * 64 + nt * 16 + quad * 4;
    uint2 rv = *(const uint2*)(row + c0);
    float4 ls = *(const float4*)(lse + c0);
    float E0 = __expf(bf_lo(rv.x) - ls.x);
    float E1 = __expf(bf_hi(rv.x) - ls.y);
    float E2 = __expf(bf_lo(rv.y) - ls.z);
    float E3 = __expf(bf_hi(rv.y) - ls.w);
    outp[nt * 2 + 0] = (unsigned)f2bf(E0) | ((unsigned)f2bf(E1) << 16);
    outp[nt * 2 + 1] = (unsigned)f2bf(E2) | ((unsigned)f2bf(E3) << 16);
  }
  uint4* dst = (uint4*)(em + (((size_t)b * 8 + w) * 64 + l) * 16);
  dst[0] = make_uint4(outp[0], outp[1], outp[2], outp[3]);
  dst[1] = make_uint4(outp[4], outp[5], outp[6], outp[7]);
}

// ---------------- the scan: 16 blocks (8 fwd + 8 bwd), 8 seqs each ----------------
// B cols duplicated 2x (col l15 <-> seq l15&7); epilogue split across the
// duplicate pair: lane sel=l15>>3 handles mt tiles {2sel, 2sel+1} only.
// P resident in registers (fp8 A-operand, mfma_scale 16x16x128); alpha in
// XOR-swizzled LDS (8 rows x 512B, 16B units ^ r7).
__global__ __launch_bounds__(512, 2) void k_scan(const unsigned char* __restrict__ P8,
                                                 const unsigned char* __restrict__ PT8,
                                                 const unsigned short* __restrict__ em,
                                                 const float* __restrict__ startv,
                                                 float* __restrict__ alphaF,
                                                 float* __restrict__ alphaB) {
  __shared__ unsigned char Abuf[8 * 512];
  __shared__ float scratch[8 * 8];           // [seq r7][wave]
  const int g = blockIdx.x, dir = g >> 3, q = g & 7;
  const int tid = threadIdx.x, w = tid >> 6, l = tid & 63;
  const int l15 = l & 15, quad = l >> 4;
  const int r7 = l15 & 7, sel = l15 >> 3;
  const int colbase = w * 64;
  const unsigned char* Pb = dir ? P8 : PT8;  // [out state][src state], x512-scaled fp8

  // A-operand fragments: A[m = out-state local l15][k = kc*128 + quad*32 + j]
  int32x8 Prf[4][4];
#pragma unroll
  for (int kc = 0; kc < 4; ++kc)
#pragma unroll
    for (int mt = 0; mt < 4; ++mt) {
      const uint4* p = (const uint4*)(Pb + (size_t)(colbase + mt * 16 + l15) * CD + kc * 128 + quad * 32);
      uint4 x0 = p[0], x1 = p[1];
      Prf[kc][mt] = (int32x8){(int)x0.x, (int)x0.y, (int)x0.z, (int)x0.w,
                              (int)x1.x, (int)x1.y, (int)x1.z, (int)x1.w};
    }

  // swizzled LDS addresses: row r7 (512B), 16B unit u stored at (u ^ r7)
  unsigned char* wr0 = Abuf + r7 * 512 + (((w * 4 + sel * 2 + 0) ^ r7) << 4) + quad * 4;
  unsigned char* wr1 = Abuf + r7 * 512 + (((w * 4 + sel * 2 + 1) ^ r7) << 4) + quad * 4;
  const unsigned char* rdrow = Abuf + r7 * 512;

  // em lane remap into the 8-group gather layout; sel picks this lane's half
  const int go = dir * 4 + (q >> 1);
  const int o = quad * 16 + (q & 1) * 8 + r7;
  const unsigned short* emp = em + (((size_t)go * 256 * 8 + w) * 64 + o) * 16 + sel * 8;
  const size_t emstride = 8 * 64 * 16;

  float Msum = 0.f;
  const float LGA = 5.54517744f;    // log 256  (gamma_A)
  const float LGP = 6.23832463f;    // log 512  (gamma_P)
  const float LGAP = 11.78350207f;  // log(256*512)

  auto tail = [&](float* v, float sub) {
    float m = fmaxf(fmaxf(fmaxf(v[0], v[1]), fmaxf(v[2], v[3])),
                    fmaxf(fmaxf(v[4], v[5]), fmaxf(v[6], v[7])));
    m = fmaxf(m, __shfl_xor(m, 8));
    m = fmaxf(m, __shfl_xor(m, 16));
    m = fmaxf(m, __shfl_xor(m, 32));
    if (sel == 0 && quad == 0) scratch[r7 * 8 + w] = m;
    __syncthreads();
    const floatx4* sr = (const floatx4*)(scratch + r7 * 8);
    floatx4 s0 = sr[0], s1 = sr[1];
    m = fmaxf(fmaxf(fmaxf(s0[0], s0[1]), fmaxf(s0[2], s0[3])),
              fmaxf(fmaxf(s1[0], s1[1]), fmaxf(s1[2], s1[3])));
    float inv = __builtin_amdgcn_rcpf(m) * 256.0f;  // gamma_A = 256
    Msum += __logf(m) - sub;
    int pk0 = __builtin_amdgcn_cvt_pk_fp8_f32(v[0] * inv, v[1] * inv, 0, false);
    pk0 = __builtin_amdgcn_cvt_pk_fp8_f32(v[2] * inv, v[3] * inv, pk0, true);
    *(int*)wr0 = pk0;
    int pk1 = __builtin_amdgcn_cvt_pk_fp8_f32(v[4] * inv, v[5] * inv, 0, false);
    pk1 = __builtin_amdgcn_cvt_pk_fp8_f32(v[6] * inv, v[7] * inv, pk1, true);
    *(int*)wr1 = pk1;
    __syncthreads();
  };

  // ---- init: A0 = exp(start) * E0 (fwd) or E0 (bwd)
  {
    uint4 e0 = *(const uint4*)emp;
    unsigned eu[4] = {e0.x, e0.y, e0.z, e0.w};
    float v[8];
#pragma unroll
    for (int i = 0; i < 2; ++i)
#pragma unroll
      for (int r = 0; r < 4; ++r) {
        int j = i * 4 + r;
        float E = (j & 1) ? bf_hi(eu[j >> 1]) : bf_lo(eu[j >> 1]);
        float st = dir ? 1.f : __expf(startv[colbase + (sel * 2 + i) * 16 + quad * 4 + r]);
        v[j] = st * E;
      }
    tail(v, LGA);
  }

  // current-step em (for s=1)
  uint4 ec = *(const uint4*)(emp + emstride);
  const int nloop = dir ? 255 : 254;
  for (int s = 1; s <= nloop; ++s) {
    int32x8 bfr[4];
#pragma unroll
    for (int kc = 0; kc < 4; ++kc) {
      int u0 = kc * 8 + quad * 2;
      uint4 x0 = *(const uint4*)(rdrow + (((u0 + 0) ^ r7) << 4));
      uint4 x1 = *(const uint4*)(rdrow + (((u0 + 1) ^ r7) << 4));
      bfr[kc] = (int32x8){(int)x0.x, (int)x0.y, (int)x0.z, (int)x0.w,
                          (int)x1.x, (int)x1.y, (int)x1.z, (int)x1.w};
    }
    // prefetch next step's em while MFMAs run
    uint4 en = *(const uint4*)(emp + (size_t)(s + 1) * emstride);
    floatx4 acc[4];
#pragma unroll
    for (int mt = 0; mt < 4; ++mt) acc[mt] = zf4();
#pragma unroll
    for (int kc = 0; kc < 4; ++kc) {
      acc[0] = mfma_mx(Prf[kc][0], bfr[kc], acc[0]);
      acc[1] = mfma_mx(Prf[kc][1], bfr[kc], acc[1]);
      acc[2] = mfma_mx(Prf[kc][2], bfr[kc], acc[2]);
      acc[3] = mfma_mx(Prf[kc][3], bfr[kc], acc[3]);
    }
    unsigned eu[4] = {ec.x, ec.y, ec.z, ec.w};
    float v[8];
#pragma unroll
    for (int i = 0; i < 2; ++i)
#pragma unroll
      for (int r = 0; r < 4; ++r) {
        int j = i * 4 + r;
        float E = (j & 1) ? bf_hi(eu[j >> 1]) : bf_lo(eu[j >> 1]);
        v[j] = acc[sel * 2 + i][r] * E;
      }
    tail(v, LGAP);
    ec = en;
  }
  // ---- final step (fwd: s=255 with em; bwd: s=256 with E=1) + store
  {
    int32x8 bfr[4];
#pragma unroll
    for (int kc = 0; kc < 4; ++kc) {
      int u0 = kc * 8 + quad * 2;
      uint4 x0 = *(const uint4*)(rdrow + (((u0 + 0) ^ r7) << 4));
      uint4 x1 = *(const uint4*)(rdrow + (((u0 + 1) ^ r7) << 4));
      bfr[kc] = (int32x8){(int)x0.x, (int)x0.y, (int)x0.z, (int)x0.w,
                          (int)x1.x, (int)x1.y, (int)x1.z, (int)x1.w};
    }
    floatx4 acc[4];
#pragma unroll
    for (int mt = 0; mt < 4; ++mt) acc[mt] = zf4();
#pragma unroll
    for (int kc = 0; kc < 4; ++kc) {
      acc[0] = mfma_mx(Prf[kc][0], bfr[kc], acc[0]);
      acc[1] = mfma_mx(Prf[kc][1], bfr[kc], acc[1]);
      acc[2] = mfma_mx(Prf[kc][2], bfr[kc], acc[2]);
      acc[3] = mfma_mx(Prf[kc][3], bfr[kc], acc[3]);
    }
    unsigned eu[4] = {ec.x, ec.y, ec.z, ec.w};
    float* dst = dir ? alphaB : alphaF;
#pragma unroll
    for (int i = 0; i < 2; ++i) {
      int mt = sel * 2 + i;
      float4 ov;
      float vv[4];
#pragma unroll
      for (int r = 0; r < 4; ++r) {
        int j = i * 4 + r;
        float E = dir ? 1.f : ((j & 1) ? bf_hi(eu[j >> 1]) : bf_lo(eu[j >> 1]));
        vv[r] = acc[mt][r] * E;
      }
      ov.x = __logf(vv[0]) + Msum - LGP;
      ov.y = __logf(vv[1]) + Msum - LGP;
      ov.z = __logf(vv[2]) + Msum - LGP;
      ov.w = __logf(vv[3]) + Msum - LGP;
      *(float4*)&dst[(size_t)(q * 8 + r7) * CD + colbase + mt * 16 + quad * 4] = ov;
    }
  }
}

// ---------------- meet in the middle: evidence = sum_n lse_c(aF + aB) ----------------
__global__ void k_meet(const float* __restrict__ aF, const float* __restrict__ aB,
                       float* __restrict__ out) {
  __shared__ float wsum[8];
  int tid = threadIdx.x, w = tid >> 6, l = tid & 63;
  float ev = 0.f;
  for (int i = 0; i < 8; ++i) {
    int n = w * 8 + i;
    float x[8];
    float m = -1e30f;
#pragma unroll
    for (int k = 0; k < 8; ++k) {
      x[k] = aF[n * CD + k * 64 + l] + aB[n * CD + k * 64 + l];
      m = fmaxf(m, x[k]);
    }
#pragma unroll
    for (int sh = 1; sh <= 32; sh <<= 1) m = fmaxf(m, __shfl_xor(m, sh));
    float s = 0.f;
#pragma unroll
    for (int k = 0; k < 8; ++k) s += __expf(x[k] - m);
#pragma unroll
    for (int sh = 1; sh <= 32; sh <<= 1) s += __shfl_xor(s, sh);
    ev += m + __logf(s);
  }
  if (l == 0) wsum[w] = ev;
  __syncthreads();
  if (tid == 0) {
    float tot = 0.f;
    for (int i = 0; i < 8; ++i) tot += wsum[i];
    out[0] = tot;
  }
}

// ---------------- host ----------------
extern "C" void kernel_launch(void* const* d_in, const int* in_sizes, int n_in,
                              void* d_out, int out_size, void* d_ws, size_t ws_size,
                              hipStream_t stream) {
  (void)in_sizes; (void)n_in; (void)out_size;
  const int* text = (const int*)d_in[0];
  const float* s_emb = (const float*)d_in[1];
  const float* s_w = (const float*)d_in[2];
  const float* s_b = (const float*)d_in[3];
  const float* s_rw = (const float*)d_in[4];
  const float* s_rb = (const float*)d_in[5];
  const float* stateE = (const float*)d_in[6];
  const float* nextE = (const float*)d_in[7];
  const float* pretE = (const float*)d_in[8];
  const float* t_rw = (const float*)d_in[9];
  const float* t_rb = (const float*)d_in[10];
  const float* termE = (const float*)d_in[11];
  float* out = (float*)d_out;

  char* ws = (char*)d_ws;
  size_t off = 0;
  auto alloc = [&](size_t bytes) {
    void* p = ws + off;
    off = (off + bytes + 255) & ~(size_t)255;
    return p;
  };
  float* w_start = (float*)alloc(CD * 4);
  unsigned short* w_tlg = (unsigned short*)alloc((size_t)CD * CD * 2);
  unsigned char* w_P8 = (unsigned char*)alloc((size_t)CD * CD);
  unsigned char* w_PT8 = (unsigned char*)alloc((size_t)CD * CD);
  float* w_fe = (float*)alloc((size_t)CD * HD * 4);
  unsigned short* w_logT = (unsigned short*)alloc((size_t)VD * CD * 2);
  float* w_part = (float*)alloc((size_t)125 * 1024 * 4);
  float* w_lse = (float*)alloc(CD * 4);
  unsigned short* w_em = (unsigned short*)alloc((size_t)8 * 256 * 512 * 16 * 2);
  float* w_aF = (float*)alloc((size_t)ND * CD * 4);
  float* w_aB = (float*)alloc((size_t)ND * CD * 4);
  if (off > ws_size) return;

  hipFuncSetAttribute(reinterpret_cast<const void*>(k_gemm),
                      hipFuncAttributeMaxDynamicSharedMemorySize, GEMM_LDS);

  k_start<<<1, 256, 0, stream>>>(s_emb, s_w, s_b, s_rw, s_rb, nextE, w_start);

  k_gemm<<<dim3(4, 4), 512, GEMM_LDS, stream>>>(stateE, nextE, w_tlg, CD);
  k_smrow<<<CD, 256, 0, stream>>>(w_tlg, w_P8);
  k_tr8<<<dim3(4, 4), 256, 0, stream>>>(w_P8, w_PT8);

  k_mlp<<<CD, 256, 0, stream>>>(pretE, t_rw, t_rb, w_fe);
  k_gemm<<<dim3(250, 4), 512, GEMM_LDS, stream>>>(termE, w_fe, w_logT, CD);

  k_lsep<<<125, 512, 0, stream>>>(w_logT, w_part);
  k_lsef<<<1, 512, 0, stream>>>(w_part, w_lse);

  k_gather<<<2048, 512, 0, stream>>>(text, w_logT, w_lse, w_em);

  k_scan<<<16, 512, 0, stream>>>(w_P8, w_PT8, w_em, w_start, w_aF, w_aB);
  k_meet<<<1, 512, 0, stream>>>(w_aF, w_aB, out);
}

// Round 6
// 752.012 us; speedup vs baseline: 1.2631x; 1.2631x over previous
//
#include <hip/hip_runtime.h>
#include <hip/hip_bf16.h>

#define HD 256
#define CD 512
#define VD 32000
#define ND 64
#define TD 512

typedef __attribute__((ext_vector_type(8))) short short8;
typedef __attribute__((ext_vector_type(4))) float floatx4;
typedef __attribute__((ext_vector_type(8))) int int32x8;

__device__ inline float bf2f(unsigned short u) {
  union { unsigned u; float f; } t; t.u = ((unsigned)u) << 16; return t.f;
}
__device__ inline unsigned short f2bf(float x) {
  union { float f; unsigned u; } t; t.f = x;
  unsigned u = t.u;
  u += 0x7FFFu + ((u >> 16) & 1u);
  return (unsigned short)(u >> 16);
}
__device__ inline float bf_lo(unsigned u) { union { unsigned u; float f; } t; t.u = u << 16; return t.f; }
__device__ inline float bf_hi(unsigned u) { union { unsigned u; float f; } t; t.u = u & 0xFFFF0000u; return t.f; }

__device__ inline floatx4 zf4() { floatx4 v; v[0] = v[1] = v[2] = v[3] = 0.f; return v; }
__device__ inline floatx4 mfma16(short8 a, short8 b, floatx4 c) {
  return __builtin_amdgcn_mfma_f32_16x16x32_bf16(a, b, c, 0, 0, 0);
}
// MX-scaled fp8 MFMA, scales pinned to 1.0 (E8M0 bias 127 = 0x7F)
__device__ inline floatx4 mfma_mx(int32x8 a, int32x8 b, floatx4 c) {
  return __builtin_amdgcn_mfma_scale_f32_16x16x128_f8f6f4(
      a, b, c, 0, 0, 0, 0x7F7F7F7F, 0, 0x7F7F7F7F);
}

// ---------------- fused start pipeline: fx -> 2 ResLayers -> log_softmax ----------------
__global__ void k_start(const float* __restrict__ emb, const float* __restrict__ W,
                        const float* __restrict__ bb, const float* __restrict__ rw,
                        const float* __restrict__ rb, const float* __restrict__ nextE,
                        float* __restrict__ startO) {
  __shared__ float x[HD], h[HD];
  __shared__ float red[4];
  int j = threadIdx.x;
  x[j] = emb[j];
  __syncthreads();
  float a = bb[j];
#pragma unroll 4
  for (int i = 0; i < HD; ++i) a += x[i] * W[i * HD + j];
  __syncthreads();
  x[j] = a;
  __syncthreads();
  for (int L = 0; L < 2; ++L) {
    const float* w1 = rw + (size_t)(L * 2 + 0) * HD * HD;
    const float* b1 = rb + (L * 2 + 0) * HD;
    const float* w2 = rw + (size_t)(L * 2 + 1) * HD * HD;
    const float* b2 = rb + (L * 2 + 1) * HD;
    float t = b1[j];
#pragma unroll 4
    for (int i = 0; i < HD; ++i) t += x[i] * w1[i * HD + j];
    t = fmaxf(t, 0.f);
    h[j] = t;
    __syncthreads();
    float o = b2[j];
#pragma unroll 4
    for (int i = 0; i < HD; ++i) o += h[i] * w2[i * HD + j];
    o = x[j] + fmaxf(o, 0.f);
    __syncthreads();
    x[j] = o;
    __syncthreads();
  }
  float lg0 = 0.f, lg1 = 0.f;
#pragma unroll 4
  for (int hh = 0; hh < HD; ++hh) {
    float xv = x[hh];
    lg0 += xv * nextE[j * HD + hh];
    lg1 += xv * nextE[(j + 256) * HD + hh];
  }
  float m = fmaxf(lg0, lg1);
#pragma unroll
  for (int sh = 1; sh <= 32; sh <<= 1) m = fmaxf(m, __shfl_xor(m, sh));
  if ((j & 63) == 0) red[j >> 6] = m;
  __syncthreads();
  m = fmaxf(fmaxf(red[0], red[1]), fmaxf(red[2], red[3]));
  __syncthreads();
  float s = __expf(lg0 - m) + __expf(lg1 - m);
#pragma unroll
  for (int sh = 1; sh <= 32; sh <<= 1) s += __shfl_xor(s, sh);
  if ((j & 63) == 0) red[j >> 6] = s;
  __syncthreads();
  s = red[0] + red[1] + red[2] + red[3];
  float ls = __logf(s);
  startO[j] = lg0 - m - ls;
  startO[j + 256] = lg1 - m - ls;
}

// x (rows x 256) -> two ResLayers -> out  (one block per row, 256 threads)
__global__ void k_mlp(const float* __restrict__ inp, const float* __restrict__ rw,
                      const float* __restrict__ rb, float* __restrict__ out) {
  __shared__ float x[HD], h[HD];
  int j = threadIdx.x;
  int row = blockIdx.x;
  x[j] = inp[row * HD + j];
  __syncthreads();
  for (int L = 0; L < 2; ++L) {
    const float* w1 = rw + (size_t)(L * 2 + 0) * HD * HD;
    const float* b1 = rb + (L * 2 + 0) * HD;
    const float* w2 = rw + (size_t)(L * 2 + 1) * HD * HD;
    const float* b2 = rb + (L * 2 + 1) * HD;
    float a = b1[j];
#pragma unroll 4
    for (int i = 0; i < HD; ++i) a += x[i] * w1[i * HD + j];
    a = fmaxf(a, 0.f);
    h[j] = a;
    __syncthreads();
    float o = b2[j];
#pragma unroll 4
    for (int i = 0; i < HD; ++i) o += h[i] * w2[i * HD + j];
    o = x[j] + fmaxf(o, 0.f);
    __syncthreads();
    x[j] = o;
    __syncthreads();
  }
  out[row * HD + j] = x[j];
}

// ---------------- generic NT GEMM (M x 256) x (N x 256)^T -> bf16 out[M][N] ----------------
#define GEMM_LDS (2 * 128 * 528)
__global__ __launch_bounds__(512) void k_gemm(const float* __restrict__ A,
                                              const float* __restrict__ B,
                                              unsigned short* __restrict__ out,
                                              int ldo) {
  extern __shared__ char smem[];
  char* sA = smem;             // [128][528 bytes] bf16, K contiguous
  char* sB = smem + 128 * 528;
  const int tid = threadIdx.x;
  const int mbase = blockIdx.x * 128, nbase = blockIdx.y * 128;
  {
    int row = tid >> 2, seg = tid & 3;
    const float4* srcA = (const float4*)(A + (size_t)(mbase + row) * HD + seg * 64);
    const float4* srcB = (const float4*)(B + (size_t)(nbase + row) * HD + seg * 64);
    uint2* dA = (uint2*)(sA + row * 528 + seg * 128);
    uint2* dB = (uint2*)(sB + row * 528 + seg * 128);
#pragma unroll
    for (int i = 0; i < 16; ++i) {
      float4 va = srcA[i];
      float4 vb = srcB[i];
      dA[i] = make_uint2((unsigned)f2bf(va.x) | ((unsigned)f2bf(va.y) << 16),
                         (unsigned)f2bf(va.z) | ((unsigned)f2bf(va.w) << 16));
      dB[i] = make_uint2((unsigned)f2bf(vb.x) | ((unsigned)f2bf(vb.y) << 16),
                         (unsigned)f2bf(vb.z) | ((unsigned)f2bf(vb.w) << 16));
    }
  }
  __syncthreads();
  const int w = tid >> 6, l = tid & 63, l15 = l & 15, quad = l >> 4;
  floatx4 acc[8];
#pragma unroll
  for (int nt = 0; nt < 8; ++nt) acc[nt] = zf4();
  const char* arow = sA + (w * 16 + l15) * 528 + quad * 16;
  const char* brow = sB + l15 * 528 + quad * 16;
#pragma unroll
  for (int kc = 0; kc < 8; ++kc) {
    short8 a = *(const short8*)(arow + kc * 64);
#pragma unroll
    for (int nt = 0; nt < 8; ++nt) {
      short8 b = *(const short8*)(brow + nt * 16 * 528 + kc * 64);
      acc[nt] = mfma16(a, b, acc[nt]);
    }
  }
#pragma unroll
  for (int nt = 0; nt < 8; ++nt)
#pragma unroll
    for (int r = 0; r < 4; ++r) {
      int m = mbase + w * 16 + quad * 4 + r;
      int n = nbase + nt * 16 + l15;
      out[(size_t)m * ldo + n] = f2bf(acc[nt][r]);
    }
}

// ---------------- transition row-softmax -> P fp8 (x512 scale) ----------------
__global__ void k_smrow(const unsigned short* __restrict__ lg, unsigned char* __restrict__ P8) {
  __shared__ float red[4];
  int row = blockIdx.x, j = threadIdx.x;
  float v0 = bf2f(lg[row * CD + j]);
  float v1 = bf2f(lg[row * CD + 256 + j]);
  float m = fmaxf(v0, v1);
#pragma unroll
  for (int sh = 1; sh <= 32; sh <<= 1) m = fmaxf(m, __shfl_xor(m, sh));
  if ((j & 63) == 0) red[j >> 6] = m;
  __syncthreads();
  m = fmaxf(fmaxf(red[0], red[1]), fmaxf(red[2], red[3]));
  __syncthreads();
  float e0 = __expf(v0 - m), e1 = __expf(v1 - m);
  float s = e0 + e1;
#pragma unroll
  for (int sh = 1; sh <= 32; sh <<= 1) s += __shfl_xor(s, sh);
  if ((j & 63) == 0) red[j >> 6] = s;
  __syncthreads();
  s = red[0] + red[1] + red[2] + red[3];
  float inv = 512.0f / s;   // gamma_P = 512 folded in
  int b0 = __builtin_amdgcn_cvt_pk_fp8_f32(e0 * inv, e0 * inv, 0, false);
  int b1 = __builtin_amdgcn_cvt_pk_fp8_f32(e1 * inv, e1 * inv, 0, false);
  P8[row * CD + j] = (unsigned char)(b0 & 0xff);
  P8[row * CD + 256 + j] = (unsigned char)(b1 & 0xff);
}

// transpose fp8 512x512: P8 -> PT8
__global__ __launch_bounds__(256) void k_tr8(const unsigned char* __restrict__ P,
                                             unsigned char* __restrict__ PT) {
  __shared__ unsigned char t[128][144];
  int rb = blockIdx.x * 128, cb = blockIdx.y * 128;
  int tid = threadIdx.x;
  {
    int r = tid >> 1, h = tid & 1;
    const uint4* src = (const uint4*)(P + (size_t)(rb + r) * CD + cb + h * 64);
    uint4* dst = (uint4*)(&t[r][h * 64]);
#pragma unroll
    for (int i = 0; i < 4; ++i) dst[i] = src[i];
  }
  __syncthreads();
  {
    int c = tid >> 1, h = tid & 1;
    unsigned char buf[64];
#pragma unroll
    for (int i = 0; i < 64; ++i) buf[i] = t[h * 64 + i][c];
    uint4* dst = (uint4*)(PT + (size_t)(cb + c) * CD + rb + h * 64);
    const uint4* s = (const uint4*)buf;
#pragma unroll
    for (int i = 0; i < 4; ++i) dst[i] = s[i];
  }
}

// ---------------- vocab log-sum-exp over columns of logT [V][C] ----------------
__global__ __launch_bounds__(512) void k_lsep(const unsigned short* __restrict__ logT,
                                              float* __restrict__ part) {
  int c = threadIdx.x, b = blockIdx.x;
  const unsigned short* p = logT + (size_t)b * 256 * CD + c;
  float m = -1e30f, s = 0.f;
  for (int i = 0; i < 256; ++i) {
    float v = bf2f(p[(size_t)i * CD]);
    float nm = fmaxf(m, v);
    s = s * __expf(m - nm) + __expf(v - nm);
    m = nm;
  }
  part[b * 1024 + c] = m;
  part[b * 1024 + 512 + c] = s;
}

__global__ void k_lsef(const float* __restrict__ part, float* __restrict__ lse) {
  int c = threadIdx.x;
  float m = -1e30f, s = 0.f;
  for (int i = 0; i < 125; ++i) {
    float mi = part[i * 1024 + c], si = part[i * 1024 + 512 + c];
    float nm = fmaxf(m, mi);
    s = s * __expf(m - nm) + si * __expf(mi - nm);
    m = nm;
  }
  lse[c] = m + __logf(s);
}

// ---------------- gather E = exp(emission log-prob) ----------------
// 8 groups of 16 seqs; lane o holds n = q*16 + (o&15),
// value j = nt*4+r at c = w*64 + nt*16 + (o>>4)*4 + r
__global__ __launch_bounds__(512) void k_gather(const int* __restrict__ text,
                                                const unsigned short* __restrict__ logT,
                                                const float* __restrict__ lse,
                                                unsigned short* __restrict__ em) {
  const int b = blockIdx.x;
  const int g = b >> 8, t = b & 255;
  const int dir = g >> 2, q = g & 3;
  const int tg = dir ? (511 - t) : t;
  const int tid = threadIdx.x, w = tid >> 6, l = tid & 63;
  const int l15 = l & 15, quad = l >> 4;
  const int n = q * 16 + l15;
  const int tok = text[n * TD + tg];
  const unsigned short* row = logT + (size_t)tok * CD;
  unsigned outp[8];
#pragma unroll
  for (int nt = 0; nt < 4; ++nt) {
    int c0 = w * 64 + nt * 16 + quad * 4;
    uint2 rv = *(const uint2*)(row + c0);
    float4 ls = *(const float4*)(lse + c0);
    float E0 = __expf(bf_lo(rv.x) - ls.x);
    float E1 = __expf(bf_hi(rv.x) - ls.y);
    float E2 = __expf(bf_lo(rv.y) - ls.z);
    float E3 = __expf(bf_hi(rv.y) - ls.w);
    outp[nt * 2 + 0] = (unsigned)f2bf(E0) | ((unsigned)f2bf(E1) << 16);
    outp[nt * 2 + 1] = (unsigned)f2bf(E2) | ((unsigned)f2bf(E3) << 16);
  }
  uint4* dst = (uint4*)(em + (((size_t)b * 8 + w) * 64 + l) * 16);
  dst[0] = make_uint4(outp[0], outp[1], outp[2], outp[3]);
  dst[1] = make_uint4(outp[4], outp[5], outp[6], outp[7]);
}

// ---------------- the scan: 16 blocks (8 fwd + 8 bwd), 8 seqs each ----------------
// B cols duplicated 2x (col l15 <-> seq l15&7); epilogue split across the
// duplicate pair: lane sel=l15>>3 handles mt tiles {2sel, 2sel+1} only.
// NOTE: acc[] must only be indexed with compile-time constants (runtime
// indices block SROA -> scratch alloca -> serial-path scratch round trips,
// the R5 regression). Selection is done with scalar ternaries instead.
__global__ __launch_bounds__(512, 2) void k_scan(const unsigned char* __restrict__ P8,
                                                 const unsigned char* __restrict__ PT8,
                                                 const unsigned short* __restrict__ em,
                                                 const float* __restrict__ startv,
                                                 float* __restrict__ alphaF,
                                                 float* __restrict__ alphaB) {
  __shared__ unsigned char Abuf[8 * 512];
  __shared__ float scratch[8 * 8];           // [seq r7][wave]
  const int g = blockIdx.x, dir = g >> 3, q = g & 7;
  const int tid = threadIdx.x, w = tid >> 6, l = tid & 63;
  const int l15 = l & 15, quad = l >> 4;
  const int r7 = l15 & 7, sel = l15 >> 3;
  const int colbase = w * 64;
  const unsigned char* Pb = dir ? P8 : PT8;  // [out state][src state], x512-scaled fp8

  // A-operand fragments: A[m = out-state local l15][k = kc*128 + quad*32 + j]
  int32x8 Prf[4][4];
#pragma unroll
  for (int kc = 0; kc < 4; ++kc)
#pragma unroll
    for (int mt = 0; mt < 4; ++mt) {
      const uint4* p = (const uint4*)(Pb + (size_t)(colbase + mt * 16 + l15) * CD + kc * 128 + quad * 32);
      uint4 x0 = p[0], x1 = p[1];
      Prf[kc][mt] = (int32x8){(int)x0.x, (int)x0.y, (int)x0.z, (int)x0.w,
                              (int)x1.x, (int)x1.y, (int)x1.z, (int)x1.w};
    }

  // swizzled LDS addresses: row r7 (512B), 16B unit u stored at (u ^ r7)
  unsigned char* wr0 = Abuf + r7 * 512 + (((w * 4 + sel * 2 + 0) ^ r7) << 4) + quad * 4;
  unsigned char* wr1 = Abuf + r7 * 512 + (((w * 4 + sel * 2 + 1) ^ r7) << 4) + quad * 4;
  const unsigned char* rdrow = Abuf + r7 * 512;

  // em lane remap into the 8-group gather layout; sel picks this lane's half
  const int go = dir * 4 + (q >> 1);
  const int o = quad * 16 + (q & 1) * 8 + r7;
  const unsigned short* emp = em + (((size_t)go * 256 * 8 + w) * 64 + o) * 16 + sel * 8;
  const size_t emstride = 8 * 64 * 16;

  float Msum = 0.f;
  const float LGA = 5.54517744f;    // log 256  (gamma_A)
  const float LGP = 6.23832463f;    // log 512  (gamma_P)
  const float LGAP = 11.78350207f;  // log(256*512)

  auto tail = [&](float* v, float sub) {
    float m = fmaxf(fmaxf(fmaxf(v[0], v[1]), fmaxf(v[2], v[3])),
                    fmaxf(fmaxf(v[4], v[5]), fmaxf(v[6], v[7])));
    m = fmaxf(m, __shfl_xor(m, 8));
    m = fmaxf(m, __shfl_xor(m, 16));
    m = fmaxf(m, __shfl_xor(m, 32));
    if (sel == 0 && quad == 0) scratch[r7 * 8 + w] = m;
    __syncthreads();
    const floatx4* sr = (const floatx4*)(scratch + r7 * 8);
    floatx4 s0 = sr[0], s1 = sr[1];
    m = fmaxf(fmaxf(fmaxf(s0[0], s0[1]), fmaxf(s0[2], s0[3])),
              fmaxf(fmaxf(s1[0], s1[1]), fmaxf(s1[2], s1[3])));
    float inv = __builtin_amdgcn_rcpf(m) * 256.0f;  // gamma_A = 256
    Msum += __logf(m) - sub;
    int pk0 = __builtin_amdgcn_cvt_pk_fp8_f32(v[0] * inv, v[1] * inv, 0, false);
    pk0 = __builtin_amdgcn_cvt_pk_fp8_f32(v[2] * inv, v[3] * inv, pk0, true);
    *(int*)wr0 = pk0;
    int pk1 = __builtin_amdgcn_cvt_pk_fp8_f32(v[4] * inv, v[5] * inv, 0, false);
    pk1 = __builtin_amdgcn_cvt_pk_fp8_f32(v[6] * inv, v[7] * inv, pk1, true);
    *(int*)wr1 = pk1;
    __syncthreads();
  };

  // ---- init: A0 = exp(start) * E0 (fwd) or E0 (bwd)
  {
    uint4 e0 = *(const uint4*)emp;
    unsigned eu[4] = {e0.x, e0.y, e0.z, e0.w};
    float v[8];
#pragma unroll
    for (int i = 0; i < 2; ++i)
#pragma unroll
      for (int r = 0; r < 4; ++r) {
        int j = i * 4 + r;
        float E = (j & 1) ? bf_hi(eu[j >> 1]) : bf_lo(eu[j >> 1]);
        float st = dir ? 1.f : __expf(startv[colbase + (sel * 2 + i) * 16 + quad * 4 + r]);
        v[j] = st * E;
      }
    tail(v, LGA);
  }

  // current-step em (for s=1)
  uint4 ec = *(const uint4*)(emp + emstride);
  const int nloop = dir ? 255 : 254;
  for (int s = 1; s <= nloop; ++s) {
    int32x8 bfr[4];
#pragma unroll
    for (int kc = 0; kc < 4; ++kc) {
      int u0 = kc * 8 + quad * 2;
      uint4 x0 = *(const uint4*)(rdrow + (((u0 + 0) ^ r7) << 4));
      uint4 x1 = *(const uint4*)(rdrow + (((u0 + 1) ^ r7) << 4));
      bfr[kc] = (int32x8){(int)x0.x, (int)x0.y, (int)x0.z, (int)x0.w,
                          (int)x1.x, (int)x1.y, (int)x1.z, (int)x1.w};
    }
    // prefetch next step's em while MFMAs run
    uint4 en = *(const uint4*)(emp + (size_t)(s + 1) * emstride);
    floatx4 acc[4];
#pragma unroll
    for (int mt = 0; mt < 4; ++mt) acc[mt] = zf4();
#pragma unroll
    for (int kc = 0; kc < 4; ++kc) {
      acc[0] = mfma_mx(Prf[kc][0], bfr[kc], acc[0]);
      acc[1] = mfma_mx(Prf[kc][1], bfr[kc], acc[1]);
      acc[2] = mfma_mx(Prf[kc][2], bfr[kc], acc[2]);
      acc[3] = mfma_mx(Prf[kc][3], bfr[kc], acc[3]);
    }
    unsigned eu[4] = {ec.x, ec.y, ec.z, ec.w};
    float v[8];
#pragma unroll
    for (int i = 0; i < 2; ++i)
#pragma unroll
      for (int r = 0; r < 4; ++r) {
        int j = i * 4 + r;
        float E = (j & 1) ? bf_hi(eu[j >> 1]) : bf_lo(eu[j >> 1]);
        // constant-index reads + scalar select (keeps acc in registers)
        float a0 = (i == 0) ? acc[0][r] : acc[1][r];
        float a1 = (i == 0) ? acc[2][r] : acc[3][r];
        v[j] = (sel ? a1 : a0) * E;
      }
    tail(v, LGAP);
    ec = en;
  }
  // ---- final step (fwd: s=255 with em; bwd: s=256 with E=1) + store
  {
    int32x8 bfr[4];
#pragma unroll
    for (int kc = 0; kc < 4; ++kc) {
      int u0 = kc * 8 + quad * 2;
      uint4 x0 = *(const uint4*)(rdrow + (((u0 + 0) ^ r7) << 4));
      uint4 x1 = *(const uint4*)(rdrow + (((u0 + 1) ^ r7) << 4));
      bfr[kc] = (int32x8){(int)x0.x, (int)x0.y, (int)x0.z, (int)x0.w,
                          (int)x1.x, (int)x1.y, (int)x1.z, (int)x1.w};
    }
    floatx4 acc[4];
#pragma unroll
    for (int mt = 0; mt < 4; ++mt) acc[mt] = zf4();
#pragma unroll
    for (int kc = 0; kc < 4; ++kc) {
      acc[0] = mfma_mx(Prf[kc][0], bfr[kc], acc[0]);
      acc[1] = mfma_mx(Prf[kc][1], bfr[kc], acc[1]);
      acc[2] = mfma_mx(Prf[kc][2], bfr[kc], acc[2]);
      acc[3] = mfma_mx(Prf[kc][3], bfr[kc], acc[3]);
    }
    unsigned eu[4] = {ec.x, ec.y, ec.z, ec.w};
    float* dst = dir ? alphaB : alphaF;
#pragma unroll
    for (int i = 0; i < 2; ++i) {
      int mt0 = i;        // tiles if sel==0
      int mt1 = 2 + i;    // tiles if sel==1
      float4 ov;
      float vv[4];
#pragma unroll
      for (int r = 0; r < 4; ++r) {
        int j = i * 4 + r;
        float E = dir ? 1.f : ((j & 1) ? bf_hi(eu[j >> 1]) : bf_lo(eu[j >> 1]));
        float a0 = acc[mt0][r];
        float a1 = acc[mt1][r];
        vv[r] = (sel ? a1 : a0) * E;
      }
      ov.x = __logf(vv[0]) + Msum - LGP;
      ov.y = __logf(vv[1]) + Msum - LGP;
      ov.z = __logf(vv[2]) + Msum - LGP;
      ov.w = __logf(vv[3]) + Msum - LGP;
      *(float4*)&dst[(size_t)(q * 8 + r7) * CD + colbase + (sel * 2 + i) * 16 + quad * 4] = ov;
    }
  }
}

// ---------------- meet in the middle: evidence = sum_n lse_c(aF + aB) ----------------
__global__ void k_meet(const float* __restrict__ aF, const float* __restrict__ aB,
                       float* __restrict__ out) {
  __shared__ float wsum[8];
  int tid = threadIdx.x, w = tid >> 6, l = tid & 63;
  float ev = 0.f;
  for (int i = 0; i < 8; ++i) {
    int n = w * 8 + i;
    float x[8];
    float m = -1e30f;
#pragma unroll
    for (int k = 0; k < 8; ++k) {
      x[k] = aF[n * CD + k * 64 + l] + aB[n * CD + k * 64 + l];
      m = fmaxf(m, x[k]);
    }
#pragma unroll
    for (int sh = 1; sh <= 32; sh <<= 1) m = fmaxf(m, __shfl_xor(m, sh));
    float s = 0.f;
#pragma unroll
    for (int k = 0; k < 8; ++k) s += __expf(x[k] - m);
#pragma unroll
    for (int sh = 1; sh <= 32; sh <<= 1) s += __shfl_xor(s, sh);
    ev += m + __logf(s);
  }
  if (l == 0) wsum[w] = ev;
  __syncthreads();
  if (tid == 0) {
    float tot = 0.f;
    for (int i = 0; i < 8; ++i) tot += wsum[i];
    out[0] = tot;
  }
}

// ---------------- host ----------------
extern "C" void kernel_launch(void* const* d_in, const int* in_sizes, int n_in,
                              void* d_out, int out_size, void* d_ws, size_t ws_size,
                              hipStream_t stream) {
  (void)in_sizes; (void)n_in; (void)out_size;
  const int* text = (const int*)d_in[0];
  const float* s_emb = (const float*)d_in[1];
  const float* s_w = (const float*)d_in[2];
  const float* s_b = (const float*)d_in[3];
  const float* s_rw = (const float*)d_in[4];
  const float* s_rb = (const float*)d_in[5];
  const float* stateE = (const float*)d_in[6];
  const float* nextE = (const float*)d_in[7];
  const float* pretE = (const float*)d_in[8];
  const float* t_rw = (const float*)d_in[9];
  const float* t_rb = (const float*)d_in[10];
  const float* termE = (const float*)d_in[11];
  float* out = (float*)d_out;

  char* ws = (char*)d_ws;
  size_t off = 0;
  auto alloc = [&](size_t bytes) {
    void* p = ws + off;
    off = (off + bytes + 255) & ~(size_t)255;
    return p;
  };
  float* w_start = (float*)alloc(CD * 4);
  unsigned short* w_tlg = (unsigned short*)alloc((size_t)CD * CD * 2);
  unsigned char* w_P8 = (unsigned char*)alloc((size_t)CD * CD);
  unsigned char* w_PT8 = (unsigned char*)alloc((size_t)CD * CD);
  float* w_fe = (float*)alloc((size_t)CD * HD * 4);
  unsigned short* w_logT = (unsigned short*)alloc((size_t)VD * CD * 2);
  float* w_part = (float*)alloc((size_t)125 * 1024 * 4);
  float* w_lse = (float*)alloc(CD * 4);
  unsigned short* w_em = (unsigned short*)alloc((size_t)8 * 256 * 512 * 16 * 2);
  float* w_aF = (float*)alloc((size_t)ND * CD * 4);
  float* w_aB = (float*)alloc((size_t)ND * CD * 4);
  if (off > ws_size) return;

  hipFuncSetAttribute(reinterpret_cast<const void*>(k_gemm),
                      hipFuncAttributeMaxDynamicSharedMemorySize, GEMM_LDS);

  k_start<<<1, 256, 0, stream>>>(s_emb, s_w, s_b, s_rw, s_rb, nextE, w_start);

  k_gemm<<<dim3(4, 4), 512, GEMM_LDS, stream>>>(stateE, nextE, w_tlg, CD);
  k_smrow<<<CD, 256, 0, stream>>>(w_tlg, w_P8);
  k_tr8<<<dim3(4, 4), 256, 0, stream>>>(w_P8, w_PT8);

  k_mlp<<<CD, 256, 0, stream>>>(pretE, t_rw, t_rb, w_fe);
  k_gemm<<<dim3(250, 4), 512, GEMM_LDS, stream>>>(termE, w_fe, w_logT, CD);

  k_lsep<<<125, 512, 0, stream>>>(w_logT, w_part);
  k_lsef<<<1, 512, 0, stream>>>(w_part, w_lse);

  k_gather<<<2048, 512, 0, stream>>>(text, w_logT, w_lse, w_em);

  k_scan<<<16, 512, 0, stream>>>(w_P8, w_PT8, w_em, w_start, w_aF, w_aB);
  k_meet<<<1, 512, 0, stream>>>(w_aF, w_aB, out);
}

// Round 7
// 608.267 us; speedup vs baseline: 1.5616x; 1.2363x over previous
//
#include <hip/hip_runtime.h>
#include <hip/hip_bf16.h>

#define HD 256
#define CD 512
#define VD 32000
#define ND 64
#define TD 512

typedef __attribute__((ext_vector_type(8))) short short8;
typedef __attribute__((ext_vector_type(4))) float floatx4;
typedef __attribute__((ext_vector_type(8))) int int32x8;

__device__ inline float bf2f(unsigned short u) {
  union { unsigned u; float f; } t; t.u = ((unsigned)u) << 16; return t.f;
}
__device__ inline unsigned short f2bf(float x) {
  union { float f; unsigned u; } t; t.f = x;
  unsigned u = t.u;
  u += 0x7FFFu + ((u >> 16) & 1u);
  return (unsigned short)(u >> 16);
}
__device__ inline float bf_lo(unsigned u) { union { unsigned u; float f; } t; t.u = u << 16; return t.f; }
__device__ inline float bf_hi(unsigned u) { union { unsigned u; float f; } t; t.u = u & 0xFFFF0000u; return t.f; }

__device__ inline floatx4 zf4() { floatx4 v; v[0] = v[1] = v[2] = v[3] = 0.f; return v; }
__device__ inline floatx4 mfma16(short8 a, short8 b, floatx4 c) {
  return __builtin_amdgcn_mfma_f32_16x16x32_bf16(a, b, c, 0, 0, 0);
}
// MX-scaled fp8 MFMA, scales pinned to 1.0 (E8M0 bias 127 = 0x7F)
__device__ inline floatx4 mfma_mx(int32x8 a, int32x8 b, floatx4 c) {
  return __builtin_amdgcn_mfma_scale_f32_16x16x128_f8f6f4(
      a, b, c, 0, 0, 0, 0x7F7F7F7F, 0, 0x7F7F7F7F);
}

// ---------------- L1: fused start pipeline (block 0) + terminal MLP (blocks 1..512) ----------------
__global__ void k_sm(const float* __restrict__ emb, const float* __restrict__ W,
                     const float* __restrict__ bb, const float* __restrict__ s_rw,
                     const float* __restrict__ s_rb, const float* __restrict__ nextE,
                     float* __restrict__ startO,
                     const float* __restrict__ pretE, const float* __restrict__ t_rw,
                     const float* __restrict__ t_rb, float* __restrict__ fe) {
  __shared__ float x[HD], h[HD];
  __shared__ float lg[2 * HD];
  __shared__ float red[8];
  const int j = threadIdx.x;
  if (blockIdx.x != 0) {
    // ---- terminal MLP row
    const int row = blockIdx.x - 1;
    x[j] = pretE[row * HD + j];
    __syncthreads();
    for (int L = 0; L < 2; ++L) {
      const float* w1 = t_rw + (size_t)(L * 2 + 0) * HD * HD;
      const float* b1 = t_rb + (L * 2 + 0) * HD;
      const float* w2 = t_rw + (size_t)(L * 2 + 1) * HD * HD;
      const float* b2 = t_rb + (L * 2 + 1) * HD;
      float a = b1[j];
#pragma unroll 4
      for (int i = 0; i < HD; ++i) a += x[i] * w1[i * HD + j];
      a = fmaxf(a, 0.f);
      h[j] = a;
      __syncthreads();
      float o = b2[j];
#pragma unroll 4
      for (int i = 0; i < HD; ++i) o += h[i] * w2[i * HD + j];
      o = x[j] + fmaxf(o, 0.f);
      __syncthreads();
      x[j] = o;
      __syncthreads();
    }
    fe[row * HD + j] = x[j];
    return;
  }
  // ---- start pipeline
  x[j] = emb[j];
  __syncthreads();
  float a = bb[j];
#pragma unroll 8
  for (int i = 0; i < HD; ++i) a += x[i] * W[i * HD + j];
  __syncthreads();
  x[j] = a;
  __syncthreads();
  for (int L = 0; L < 2; ++L) {
    const float* w1 = s_rw + (size_t)(L * 2 + 0) * HD * HD;
    const float* b1 = s_rb + (L * 2 + 0) * HD;
    const float* w2 = s_rw + (size_t)(L * 2 + 1) * HD * HD;
    const float* b2 = s_rb + (L * 2 + 1) * HD;
    float t = b1[j];
#pragma unroll 8
    for (int i = 0; i < HD; ++i) t += x[i] * w1[i * HD + j];
    t = fmaxf(t, 0.f);
    h[j] = t;
    __syncthreads();
    float o = b2[j];
#pragma unroll 8
    for (int i = 0; i < HD; ++i) o += h[i] * w2[i * HD + j];
    o = x[j] + fmaxf(o, 0.f);
    __syncthreads();
    x[j] = o;
    __syncthreads();
  }
  // logits: wave-per-rows, lanes over K (coalesced nextE reads)
  {
    const int w = j >> 6, l = j & 63;
    for (int rr = w * 128; rr < (w + 1) * 128; ++rr) {
      float s = 0.f;
#pragma unroll
      for (int k = 0; k < 4; ++k) s += x[l + k * 64] * nextE[rr * HD + l + k * 64];
#pragma unroll
      for (int off = 32; off >= 1; off >>= 1) s += __shfl_down(s, off);
      if (l == 0) lg[rr] = s;
    }
  }
  __syncthreads();
  float lg0 = lg[j], lg1 = lg[j + 256];
  float m = fmaxf(lg0, lg1);
#pragma unroll
  for (int sh = 1; sh <= 32; sh <<= 1) m = fmaxf(m, __shfl_xor(m, sh));
  if ((j & 63) == 0) red[j >> 6] = m;
  __syncthreads();
  m = fmaxf(fmaxf(red[0], red[1]), fmaxf(red[2], red[3]));
  __syncthreads();
  float s = __expf(lg0 - m) + __expf(lg1 - m);
#pragma unroll
  for (int sh = 1; sh <= 32; sh <<= 1) s += __shfl_xor(s, sh);
  if ((j & 63) == 0) red[j >> 6] = s;
  __syncthreads();
  s = red[0] + red[1] + red[2] + red[3];
  float ls = __logf(s);
  startO[j] = lg0 - m - ls;
  startO[j + 256] = lg1 - m - ls;
}

// ---------------- L2: fused GEMMs. blocks 0..249: termE x fe^T -> logT (full 128x512 row-block);
// blocks 250..253: stateE x nextE^T -> tlg. A staged once; B re-staged per 128-col panel. ----------------
#define GEMM_LDS (2 * 128 * 528)
__global__ __launch_bounds__(512) void k_gemm2(const float* __restrict__ A0,
                                               const float* __restrict__ B0,
                                               unsigned short* __restrict__ out0,
                                               const float* __restrict__ A1,
                                               const float* __restrict__ B1,
                                               unsigned short* __restrict__ out1) {
  extern __shared__ char smem[];
  char* sA = smem;             // [128][528 bytes] bf16, K contiguous
  char* sB = smem + 128 * 528;
  const int tid = threadIdx.x;
  const int bx = blockIdx.x;
  const float* A; const float* B; unsigned short* out; int mbase;
  if (bx < 250) { A = A0; B = B0; out = out0; mbase = bx * 128; }
  else          { A = A1; B = B1; out = out1; mbase = (bx - 250) * 128; }
  const int row = tid >> 2, seg = tid & 3;
  {
    const float4* srcA = (const float4*)(A + (size_t)(mbase + row) * HD + seg * 64);
    uint2* dA = (uint2*)(sA + row * 528 + seg * 128);
#pragma unroll
    for (int i = 0; i < 16; ++i) {
      float4 va = srcA[i];
      dA[i] = make_uint2((unsigned)f2bf(va.x) | ((unsigned)f2bf(va.y) << 16),
                         (unsigned)f2bf(va.z) | ((unsigned)f2bf(va.w) << 16));
    }
  }
  const int w = tid >> 6, l = tid & 63, l15 = l & 15, quad = l >> 4;
  const char* arow = sA + (w * 16 + l15) * 528 + quad * 16;
  const char* brow = sB + l15 * 528 + quad * 16;
  for (int ny = 0; ny < 4; ++ny) {
    __syncthreads();  // prev MFMA reads done (and sA visible on first iter)
    {
      const float4* srcB = (const float4*)(B + (size_t)(ny * 128 + row) * HD + seg * 64);
      uint2* dB = (uint2*)(sB + row * 528 + seg * 128);
#pragma unroll
      for (int i = 0; i < 16; ++i) {
        float4 vb = srcB[i];
        dB[i] = make_uint2((unsigned)f2bf(vb.x) | ((unsigned)f2bf(vb.y) << 16),
                           (unsigned)f2bf(vb.z) | ((unsigned)f2bf(vb.w) << 16));
      }
    }
    __syncthreads();
    floatx4 acc[8];
#pragma unroll
    for (int nt = 0; nt < 8; ++nt) acc[nt] = zf4();
#pragma unroll
    for (int kc = 0; kc < 8; ++kc) {
      short8 a = *(const short8*)(arow + kc * 64);
#pragma unroll
      for (int nt = 0; nt < 8; ++nt) {
        short8 b = *(const short8*)(brow + nt * 16 * 528 + kc * 64);
        acc[nt] = mfma16(a, b, acc[nt]);
      }
    }
#pragma unroll
    for (int nt = 0; nt < 8; ++nt)
#pragma unroll
      for (int r = 0; r < 4; ++r) {
        int m = mbase + w * 16 + quad * 4 + r;
        int n = ny * 128 + nt * 16 + l15;
        out[(size_t)m * CD + n] = f2bf(acc[nt][r]);
      }
  }
}

// ---------------- L3: fused transition softmax (blocks 0..511, writes P8+PT8)
// + vocab lse partials (blocks 512..636) + final lse by last-finisher ----------------
__global__ __launch_bounds__(512) void k_sml(const unsigned short* __restrict__ tlg,
                                             unsigned char* __restrict__ P8,
                                             unsigned char* __restrict__ PT8,
                                             const unsigned short* __restrict__ logT,
                                             float* __restrict__ part,
                                             float* __restrict__ lse,
                                             unsigned int* __restrict__ cnt) {
  __shared__ float red[8];
  __shared__ int s_last;
  const int tid = threadIdx.x;
  if (blockIdx.x < 512) {
    // transition row softmax -> fp8 (x512), write P and P^T
    const int row = blockIdx.x;
    float v = bf2f(tlg[row * CD + tid]);
    float m = v;
#pragma unroll
    for (int sh = 1; sh <= 32; sh <<= 1) m = fmaxf(m, __shfl_xor(m, sh));
    if ((tid & 63) == 0) red[tid >> 6] = m;
    __syncthreads();
    m = fmaxf(fmaxf(fmaxf(red[0], red[1]), fmaxf(red[2], red[3])),
              fmaxf(fmaxf(red[4], red[5]), fmaxf(red[6], red[7])));
    __syncthreads();
    float e = __expf(v - m);
    float s = e;
#pragma unroll
    for (int sh = 1; sh <= 32; sh <<= 1) s += __shfl_xor(s, sh);
    if ((tid & 63) == 0) red[tid >> 6] = s;
    __syncthreads();
    s = red[0] + red[1] + red[2] + red[3] + red[4] + red[5] + red[6] + red[7];
    float inv = 512.0f / s;  // gamma_P = 512
    int b0 = __builtin_amdgcn_cvt_pk_fp8_f32(e * inv, e * inv, 0, false);
    unsigned char byte = (unsigned char)(b0 & 0xff);
    P8[row * CD + tid] = byte;
    PT8[(size_t)tid * CD + row] = byte;
    return;
  }
  // vocab lse partials
  const int b = blockIdx.x - 512, c = tid;
  {
    const unsigned short* p = logT + (size_t)b * 256 * CD + c;
    float m = -1e30f, s = 0.f;
    for (int i = 0; i < 256; ++i) {
      float v = bf2f(p[(size_t)i * CD]);
      float nm = fmaxf(m, v);
      s = s * __expf(m - nm) + __expf(v - nm);
      m = nm;
    }
    part[b * 1024 + c] = m;
    part[b * 1024 + 512 + c] = s;
  }
  __threadfence();
  if (tid == 0) s_last = (atomicAdd(cnt, 1u) == 124u) ? 1 : 0;
  __syncthreads();
  if (s_last) {
    __threadfence();
    float m = -1e30f, s = 0.f;
    for (int i = 0; i < 125; ++i) {
      float mi = part[i * 1024 + c], si = part[i * 1024 + 512 + c];
      float nm = fmaxf(m, mi);
      s = s * __expf(m - nm) + si * __expf(mi - nm);
      m = nm;
    }
    lse[c] = m + __logf(s);
  }
}

// ---------------- L4: gather E = exp(emission log-prob) ----------------
__global__ __launch_bounds__(512) void k_gather(const int* __restrict__ text,
                                                const unsigned short* __restrict__ logT,
                                                const float* __restrict__ lse,
                                                unsigned short* __restrict__ em) {
  const int b = blockIdx.x;
  const int g = b >> 8, t = b & 255;
  const int dir = g >> 2, q = g & 3;
  const int tg = dir ? (511 - t) : t;
  const int tid = threadIdx.x, w = tid >> 6, l = tid & 63;
  const int l15 = l & 15, quad = l >> 4;
  const int n = q * 16 + l15;
  const int tok = text[n * TD + tg];
  const unsigned short* row = logT + (size_t)tok * CD;
  unsigned outp[8];
#pragma unroll
  for (int nt = 0; nt < 4; ++nt) {
    int c0 = w * 64 + nt * 16 + quad * 4;
    uint2 rv = *(const uint2*)(row + c0);
    float4 ls = *(const float4*)(lse + c0);
    float E0 = __expf(bf_lo(rv.x) - ls.x);
    float E1 = __expf(bf_hi(rv.x) - ls.y);
    float E2 = __expf(bf_lo(rv.y) - ls.z);
    float E3 = __expf(bf_hi(rv.y) - ls.w);
    outp[nt * 2 + 0] = (unsigned)f2bf(E0) | ((unsigned)f2bf(E1) << 16);
    outp[nt * 2 + 1] = (unsigned)f2bf(E2) | ((unsigned)f2bf(E3) << 16);
  }
  uint4* dst = (uint4*)(em + (((size_t)b * 8 + w) * 64 + l) * 16);
  dst[0] = make_uint4(outp[0], outp[1], outp[2], outp[3]);
  dst[1] = make_uint4(outp[4], outp[5], outp[6], outp[7]);
}

// ---------------- L5: the scan (16 blocks) + meet-in-the-middle by last finisher ----------------
// Scan body identical to R6 (best known). acc[] only constant-indexed (R5 lesson).
__global__ __launch_bounds__(512, 2) void k_scan(const unsigned char* __restrict__ P8,
                                                 const unsigned char* __restrict__ PT8,
                                                 const unsigned short* __restrict__ em,
                                                 const float* __restrict__ startv,
                                                 float* __restrict__ alphaF,
                                                 float* __restrict__ alphaB,
                                                 unsigned int* __restrict__ cnt,
                                                 float* __restrict__ out) {
  __shared__ unsigned char Abuf[8 * 512];
  __shared__ float scratch[8 * 8];           // [seq r7][wave]
  __shared__ int s_last;
  const int g = blockIdx.x, dir = g >> 3, q = g & 7;
  const int tid = threadIdx.x, w = tid >> 6, l = tid & 63;
  const int l15 = l & 15, quad = l >> 4;
  const int r7 = l15 & 7, sel = l15 >> 3;
  const int colbase = w * 64;
  const unsigned char* Pb = dir ? P8 : PT8;  // [out state][src state], x512-scaled fp8

  int32x8 Prf[4][4];
#pragma unroll
  for (int kc = 0; kc < 4; ++kc)
#pragma unroll
    for (int mt = 0; mt < 4; ++mt) {
      const uint4* p = (const uint4*)(Pb + (size_t)(colbase + mt * 16 + l15) * CD + kc * 128 + quad * 32);
      uint4 x0 = p[0], x1 = p[1];
      Prf[kc][mt] = (int32x8){(int)x0.x, (int)x0.y, (int)x0.z, (int)x0.w,
                              (int)x1.x, (int)x1.y, (int)x1.z, (int)x1.w};
    }

  unsigned char* wr0 = Abuf + r7 * 512 + (((w * 4 + sel * 2 + 0) ^ r7) << 4) + quad * 4;
  unsigned char* wr1 = Abuf + r7 * 512 + (((w * 4 + sel * 2 + 1) ^ r7) << 4) + quad * 4;
  const unsigned char* rdrow = Abuf + r7 * 512;

  const int go = dir * 4 + (q >> 1);
  const int o = quad * 16 + (q & 1) * 8 + r7;
  const unsigned short* emp = em + (((size_t)go * 256 * 8 + w) * 64 + o) * 16 + sel * 8;
  const size_t emstride = 8 * 64 * 16;

  float Msum = 0.f;
  const float LGA = 5.54517744f;    // log 256  (gamma_A)
  const float LGP = 6.23832463f;    // log 512  (gamma_P)
  const float LGAP = 11.78350207f;  // log(256*512)

  auto tail = [&](float* v, float sub) {
    float m = fmaxf(fmaxf(fmaxf(v[0], v[1]), fmaxf(v[2], v[3])),
                    fmaxf(fmaxf(v[4], v[5]), fmaxf(v[6], v[7])));
    m = fmaxf(m, __shfl_xor(m, 8));
    m = fmaxf(m, __shfl_xor(m, 16));
    m = fmaxf(m, __shfl_xor(m, 32));
    if (sel == 0 && quad == 0) scratch[r7 * 8 + w] = m;
    __syncthreads();
    const floatx4* sr = (const floatx4*)(scratch + r7 * 8);
    floatx4 s0 = sr[0], s1 = sr[1];
    m = fmaxf(fmaxf(fmaxf(s0[0], s0[1]), fmaxf(s0[2], s0[3])),
              fmaxf(fmaxf(s1[0], s1[1]), fmaxf(s1[2], s1[3])));
    float inv = __builtin_amdgcn_rcpf(m) * 256.0f;  // gamma_A = 256
    Msum += __logf(m) - sub;
    int pk0 = __builtin_amdgcn_cvt_pk_fp8_f32(v[0] * inv, v[1] * inv, 0, false);
    pk0 = __builtin_amdgcn_cvt_pk_fp8_f32(v[2] * inv, v[3] * inv, pk0, true);
    *(int*)wr0 = pk0;
    int pk1 = __builtin_amdgcn_cvt_pk_fp8_f32(v[4] * inv, v[5] * inv, 0, false);
    pk1 = __builtin_amdgcn_cvt_pk_fp8_f32(v[6] * inv, v[7] * inv, pk1, true);
    *(int*)wr1 = pk1;
    __syncthreads();
  };

  // ---- init: A0 = exp(start) * E0 (fwd) or E0 (bwd)
  {
    uint4 e0 = *(const uint4*)emp;
    unsigned eu[4] = {e0.x, e0.y, e0.z, e0.w};
    float v[8];
#pragma unroll
    for (int i = 0; i < 2; ++i)
#pragma unroll
      for (int r = 0; r < 4; ++r) {
        int j = i * 4 + r;
        float E = (j & 1) ? bf_hi(eu[j >> 1]) : bf_lo(eu[j >> 1]);
        float st = dir ? 1.f : __expf(startv[colbase + (sel * 2 + i) * 16 + quad * 4 + r]);
        v[j] = st * E;
      }
    tail(v, LGA);
  }

  uint4 ec = *(const uint4*)(emp + emstride);
  const int nloop = dir ? 255 : 254;
  for (int s = 1; s <= nloop; ++s) {
    int32x8 bfr[4];
#pragma unroll
    for (int kc = 0; kc < 4; ++kc) {
      int u0 = kc * 8 + quad * 2;
      uint4 x0 = *(const uint4*)(rdrow + (((u0 + 0) ^ r7) << 4));
      uint4 x1 = *(const uint4*)(rdrow + (((u0 + 1) ^ r7) << 4));
      bfr[kc] = (int32x8){(int)x0.x, (int)x0.y, (int)x0.z, (int)x0.w,
                          (int)x1.x, (int)x1.y, (int)x1.z, (int)x1.w};
    }
    uint4 en = *(const uint4*)(emp + (size_t)(s + 1) * emstride);
    floatx4 acc[4];
#pragma unroll
    for (int mt = 0; mt < 4; ++mt) acc[mt] = zf4();
#pragma unroll
    for (int kc = 0; kc < 4; ++kc) {
      acc[0] = mfma_mx(Prf[kc][0], bfr[kc], acc[0]);
      acc[1] = mfma_mx(Prf[kc][1], bfr[kc], acc[1]);
      acc[2] = mfma_mx(Prf[kc][2], bfr[kc], acc[2]);
      acc[3] = mfma_mx(Prf[kc][3], bfr[kc], acc[3]);
    }
    unsigned eu[4] = {ec.x, ec.y, ec.z, ec.w};
    float v[8];
#pragma unroll
    for (int i = 0; i < 2; ++i)
#pragma unroll
      for (int r = 0; r < 4; ++r) {
        int j = i * 4 + r;
        float E = (j & 1) ? bf_hi(eu[j >> 1]) : bf_lo(eu[j >> 1]);
        float a0 = (i == 0) ? acc[0][r] : acc[1][r];
        float a1 = (i == 0) ? acc[2][r] : acc[3][r];
        v[j] = (sel ? a1 : a0) * E;
      }
    tail(v, LGAP);
    ec = en;
  }
  // ---- final step + store
  {
    int32x8 bfr[4];
#pragma unroll
    for (int kc = 0; kc < 4; ++kc) {
      int u0 = kc * 8 + quad * 2;
      uint4 x0 = *(const uint4*)(rdrow + (((u0 + 0) ^ r7) << 4));
      uint4 x1 = *(const uint4*)(rdrow + (((u0 + 1) ^ r7) << 4));
      bfr[kc] = (int32x8){(int)x0.x, (int)x0.y, (int)x0.z, (int)x0.w,
                          (int)x1.x, (int)x1.y, (int)x1.z, (int)x1.w};
    }
    floatx4 acc[4];
#pragma unroll
    for (int mt = 0; mt < 4; ++mt) acc[mt] = zf4();
#pragma unroll
    for (int kc = 0; kc < 4; ++kc) {
      acc[0] = mfma_mx(Prf[kc][0], bfr[kc], acc[0]);
      acc[1] = mfma_mx(Prf[kc][1], bfr[kc], acc[1]);
      acc[2] = mfma_mx(Prf[kc][2], bfr[kc], acc[2]);
      acc[3] = mfma_mx(Prf[kc][3], bfr[kc], acc[3]);
    }
    unsigned eu[4] = {ec.x, ec.y, ec.z, ec.w};
    float* dst = dir ? alphaB : alphaF;
#pragma unroll
    for (int i = 0; i < 2; ++i) {
      int mt0 = i, mt1 = 2 + i;
      float4 ov;
      float vv[4];
#pragma unroll
      for (int r = 0; r < 4; ++r) {
        int j = i * 4 + r;
        float E = dir ? 1.f : ((j & 1) ? bf_hi(eu[j >> 1]) : bf_lo(eu[j >> 1]));
        float a0 = acc[mt0][r];
        float a1 = acc[mt1][r];
        vv[r] = (sel ? a1 : a0) * E;
      }
      ov.x = __logf(vv[0]) + Msum - LGP;
      ov.y = __logf(vv[1]) + Msum - LGP;
      ov.z = __logf(vv[2]) + Msum - LGP;
      ov.w = __logf(vv[3]) + Msum - LGP;
      *(float4*)&dst[(size_t)(q * 8 + r7) * CD + colbase + (sel * 2 + i) * 16 + quad * 4] = ov;
    }
  }
  // ---- last-finisher meet: evidence = sum_n lse_c(aF + aB)
  __threadfence();
  if (tid == 0) s_last = (atomicAdd(cnt, 1u) == 15u) ? 1 : 0;
  __syncthreads();
  if (s_last) {
    __threadfence();
    float ev = 0.f;
    for (int i = 0; i < 8; ++i) {
      int n = w * 8 + i;
      float x[8];
      float m = -1e30f;
#pragma unroll
      for (int k = 0; k < 8; ++k) {
        x[k] = alphaF[n * CD + k * 64 + l] + alphaB[n * CD + k * 64 + l];
        m = fmaxf(m, x[k]);
      }
#pragma unroll
      for (int sh = 1; sh <= 32; sh <<= 1) m = fmaxf(m, __shfl_xor(m, sh));
      float s = 0.f;
#pragma unroll
      for (int k = 0; k < 8; ++k) s += __expf(x[k] - m);
#pragma unroll
      for (int sh = 1; sh <= 32; sh <<= 1) s += __shfl_xor(s, sh);
      ev += m + __logf(s);
    }
    if (l == 0) scratch[w] = ev;
    __syncthreads();
    if (tid == 0) {
      float tot = 0.f;
      for (int i = 0; i < 8; ++i) tot += scratch[i];
      out[0] = tot;
    }
  }
}

// ---------------- host ----------------
extern "C" void kernel_launch(void* const* d_in, const int* in_sizes, int n_in,
                              void* d_out, int out_size, void* d_ws, size_t ws_size,
                              hipStream_t stream) {
  (void)in_sizes; (void)n_in; (void)out_size;
  const int* text = (const int*)d_in[0];
  const float* s_emb = (const float*)d_in[1];
  const float* s_w = (const float*)d_in[2];
  const float* s_b = (const float*)d_in[3];
  const float* s_rw = (const float*)d_in[4];
  const float* s_rb = (const float*)d_in[5];
  const float* stateE = (const float*)d_in[6];
  const float* nextE = (const float*)d_in[7];
  const float* pretE = (const float*)d_in[8];
  const float* t_rw = (const float*)d_in[9];
  const float* t_rb = (const float*)d_in[10];
  const float* termE = (const float*)d_in[11];
  float* out = (float*)d_out;

  char* ws = (char*)d_ws;
  size_t off = 0;
  auto alloc = [&](size_t bytes) {
    void* p = ws + off;
    off = (off + bytes + 255) & ~(size_t)255;
    return p;
  };
  unsigned int* w_cnt = (unsigned int*)alloc(256);  // [0]=scan, [1]=lsep
  float* w_start = (float*)alloc(CD * 4);
  unsigned short* w_tlg = (unsigned short*)alloc((size_t)CD * CD * 2);
  unsigned char* w_P8 = (unsigned char*)alloc((size_t)CD * CD);
  unsigned char* w_PT8 = (unsigned char*)alloc((size_t)CD * CD);
  float* w_fe = (float*)alloc((size_t)CD * HD * 4);
  unsigned short* w_logT = (unsigned short*)alloc((size_t)VD * CD * 2);
  float* w_part = (float*)alloc((size_t)125 * 1024 * 4);
  float* w_lse = (float*)alloc(CD * 4);
  unsigned short* w_em = (unsigned short*)alloc((size_t)8 * 256 * 512 * 16 * 2);
  float* w_aF = (float*)alloc((size_t)ND * CD * 4);
  float* w_aB = (float*)alloc((size_t)ND * CD * 4);
  if (off > ws_size) return;

  hipFuncSetAttribute(reinterpret_cast<const void*>(k_gemm2),
                      hipFuncAttributeMaxDynamicSharedMemorySize, GEMM_LDS);

  hipMemsetAsync(w_cnt, 0, 256, stream);

  k_sm<<<513, 256, 0, stream>>>(s_emb, s_w, s_b, s_rw, s_rb, nextE, w_start,
                                pretE, t_rw, t_rb, w_fe);
  k_gemm2<<<254, 512, GEMM_LDS, stream>>>(termE, w_fe, w_logT, stateE, nextE, w_tlg);
  k_sml<<<637, 512, 0, stream>>>(w_tlg, w_P8, w_PT8, w_logT, w_part, w_lse, w_cnt + 1);
  k_gather<<<2048, 512, 0, stream>>>(text, w_logT, w_lse, w_em);
  k_scan<<<16, 512, 0, stream>>>(w_P8, w_PT8, w_em, w_start, w_aF, w_aB, w_cnt, out);
}